// Round 13
// baseline (311.323 us; speedup 1.0000x reference)
//
#include <hip/hip_runtime.h>
#include <hip/hip_fp16.h>

#define BB 512
#define TT 2048

typedef _Float16 half2v __attribute__((ext_vector_type(2)));

// ---------- fast math helpers ----------
__device__ __forceinline__ float fexp2(float x){ return __builtin_amdgcn_exp2f(x); }
__device__ __forceinline__ float frcp(float x){ return __builtin_amdgcn_rcpf(x); }

#define QB(v, ctrl) __int_as_float(__builtin_amdgcn_mov_dpp(__float_as_int(v), (ctrl), 0xF, 0xF, true))
#define RL(v, l)    __builtin_amdgcn_readlane((v), (l))

// ---------- fused producer/consumer, round 13: flag sync instead of barriers ----------
// = round 6 (measured optimum, 235us kernel) with ONE structural change: the 32
// per-chunk __syncthreads are replaced by a one-directional LDS flag handshake.
// Rationale: the +35 cy/step residual over the bare 240-cy chain survived five
// falsifications (I$, setprio, producer-load drain, chunk size, producer lateness);
// the un-isolated suspect is the barrier itself -- each __syncthreads forces BOTH
// waves through rendezvous + s_waitcnt vmcnt(0) lgkmcnt(0), 32x. The producer is
// always ~10K cy early, so the consumer pays rendezvous+drain for nothing.
//   producer: FILL -> s_waitcnt lgkmcnt(0) -> volatile pflag=P. Spins on
//             cflag >= P-2 before overwriting a buffer (it has huge slack).
//   consumer: spins on pflag >= C (1 volatile ds_read when producer early),
//             sched_barrier(0) fence (guards against ds_read hoisting, rule #18),
//             CONSUME (byte-identical), sched_barrier(0), volatile cflag=C.
//             NO vmcnt/lgkmcnt drains, no rendezvous, anywhere in its main loop.
// Math/layout/FILL/CONSUME identical to round 6. One initial __syncthreads stays.
__global__ __launch_bounds__(128, 1) void k_pcf(
    const float* __restrict__ x,
    const float* __restrict__ Wih,
    const float* __restrict__ Whh,
    const float* __restrict__ bih,
    const float* __restrict__ bhh,
    const float* __restrict__ fcw,
    const float* __restrict__ fcb,
    float* __restrict__ out)
{
  __shared__ unsigned short xgb[2][8][424];   // [buf][tg][53 rows x 8 u]
  __shared__ int flg[2];                      // flg[0]=last chunk produced, flg[1]=last consumed

  const int tid  = threadIdx.x;
  const int wid  = tid >> 6;
  const int lane = tid & 63;
  const int b    = blockIdx.x;

  // ---- producer state (persists across chunk loop)
  float xr[13];
  const int  tgl = lane >> 3, u = lane & 7;
  const float* xbase = x + ((size_t)b*TT + tgl*8 + u)*13;   // t = c*64 + tgl*8 + u
  unsigned short fc16 = 0;

  // ---- consumer state (persists across chunk loop; k_rec7 verbatim)
  float w[13];
  float gm = 1.f, ga = 0.f, fcbias = 0.f;
  int   e = 0;
  float h = 0.f, c_ = 0.f;            // c_ carries -2*log2e*c
  float hb0=0,hb1=0,hb2=0,hb3=0,hb4=0,hb5=0,hb6=0,hb7=0,hb8=0,hb9=0,hb10=0,hb11=0,hb12=0;
  float p0=0,p1=0,p2=0,p3=0,p4=0,p5=0,p6=0,p7=0;
  float* op = out + (size_t)b*TT;
  bool first = true;

// producer: load chunk c_'s 13 x values (coalesced per-lane dwords; issued one
// chunk ahead -- the full consumer chunk (~15K cy) covers HBM latency)
#define XLOAD(c_) do {                                                        \
    const float* p_ = xbase + (size_t)(c_)*64*13;                             \
    _Pragma("unroll")                                                         \
    for (int k=0;k<13;++k) xr[k] = p_[k];                                     \
  } while(0)

// producer: compute + write one chunk in the exact k_xg3 row format
#define FILL(bi_) do {                                                        \
    unsigned short* dst_ = &xgb[bi_][tgl][0];                                 \
    _Pragma("unroll 4")                                                       \
    for (int g=0; g<52; ++g){                                                 \
      float acc = bih[g] + bhh[g];                                            \
      _Pragma("unroll")                                                       \
      for (int k=0;k<13;++k) acc = fmaf(Wih[g*13+k], xr[k], acc);             \
      const float sc = (g>=26 && g<39) ? -2.8853900817779268f                 \
                                       : -1.4426950408889634f;                \
      dst_[g*8 + u] = __half_as_ushort(__float2half(acc*sc));                 \
    }                                                                         \
    dst_[52*8 + u] = fc16;                                                    \
  } while(0)

#define CAPTURE(gv_, u_) do {                                                 \
    if ((u_)==1) p0=(gv_); else if ((u_)==2) p1=(gv_);                        \
    else if ((u_)==3) p2=(gv_); else if ((u_)==4) p3=(gv_);                   \
    else if ((u_)==5) p4=(gv_); else if ((u_)==6) p5=(gv_);                   \
    else if ((u_)==7) p6=(gv_);                                               \
    else { p7=(gv_);                                                          \
      if (!first){                                                            \
        if (lane == 52){                                                      \
          float4* o4 = (float4*)op;                                           \
          o4[0] = make_float4(p0,p1,p2,p3);                                   \
          o4[1] = make_float4(p4,p5,p6,p7);                                   \
        }                                                                     \
        op += 8;                                                              \
      }                                                                       \
      first = false;                                                          \
    }                                                                         \
  } while(0)

#define STEP(xv_, u_) do {                                                    \
    float dA = fmaf(w[0], hb0, (xv_));                                        \
    dA = fmaf(w[1], hb1, dA);                                                 \
    dA = fmaf(w[2], hb2, dA);                                                 \
    dA = fmaf(w[3], hb3, dA);                                                 \
    dA = fmaf(w[4], hb4, dA);                                                 \
    float dB = w[5]*hb5;                                                      \
    dB = fmaf(w[6], hb6, dB);                                                 \
    dB = fmaf(w[7], hb7, dB);                                                 \
    dB = fmaf(w[8], hb8, dB);                                                 \
    float dC = w[9]*hb9;                                                      \
    dC = fmaf(w[10], hb10, dC);                                               \
    dC = fmaf(w[11], hb11, dC);                                               \
    dC = fmaf(w[12], hb12, dC);                                               \
    float s  = (dB + dC) + dA;                                                \
    float r  = frcp(1.f + fexp2(s));                                          \
    float g  = fmaf(gm, r, ga);                                               \
    CAPTURE(g, u_);                                                           \
    float ggb = QB(g, 0xAA);                                                  \
    float gfb = QB(g, 0x55);                                                  \
    float gob = QB(g, 0xFF);                                                  \
    float go2 = gob + gob;                                                    \
    c_ = fmaf(gfb, c_, g*ggb);                                                \
    float r2 = frcp(1.f + fexp2(c_));                                         \
    h = fmaf(go2, r2, -gob);                                                  \
    int hv_ = __float_as_int(h);                                              \
    hb0  = __int_as_float(RL(hv_, 0));                                        \
    hb1  = __int_as_float(RL(hv_, 4));                                        \
    hb2  = __int_as_float(RL(hv_, 8));                                        \
    hb3  = __int_as_float(RL(hv_, 12));                                       \
    hb4  = __int_as_float(RL(hv_, 16));                                       \
    hb5  = __int_as_float(RL(hv_, 20));                                       \
    hb6  = __int_as_float(RL(hv_, 24));                                       \
    hb7  = __int_as_float(RL(hv_, 28));                                       \
    hb8  = __int_as_float(RL(hv_, 32));                                       \
    hb9  = __int_as_float(RL(hv_, 36));                                       \
    hb10 = __int_as_float(RL(hv_, 40));                                       \
    hb11 = __int_as_float(RL(hv_, 44));                                       \
    hb12 = __int_as_float(RL(hv_, 48));                                       \
  } while(0)

#define XLO(w_) (float)(__builtin_bit_cast(half2v, (w_)).x)
#define XHI(w_) (float)(__builtin_bit_cast(half2v, (w_)).y)

#define STEP8(Q) do {                                                         \
    STEP(XLO(Q.x), 0); STEP(XHI(Q.x), 1);                                     \
    STEP(XLO(Q.y), 2); STEP(XHI(Q.y), 3);                                     \
    STEP(XLO(Q.z), 4); STEP(XHI(Q.z), 5);                                     \
    STEP(XLO(Q.w), 6); STEP(XHI(Q.w), 7);                                     \
  } while(0)

// consumer: one chunk = 8 tg rows, k_rec7's uint4 row loads from LDS
#define CONSUME(bi_) do {                                                     \
    const char* base_ = (const char*)&xgb[bi_][0][0] + (size_t)e*16;          \
    uint4 r0 = *(const uint4*)(base_ + 0*848);                                \
    uint4 r1 = *(const uint4*)(base_ + 1*848);                                \
    uint4 r2 = *(const uint4*)(base_ + 2*848);                                \
    uint4 r3 = *(const uint4*)(base_ + 3*848);                                \
    uint4 r4 = *(const uint4*)(base_ + 4*848);                                \
    uint4 r5 = *(const uint4*)(base_ + 5*848);                                \
    uint4 r6 = *(const uint4*)(base_ + 6*848);                                \
    uint4 r7 = *(const uint4*)(base_ + 7*848);                                \
    STEP8(r0); STEP8(r1); STEP8(r2); STEP8(r3);                               \
    STEP8(r4); STEP8(r5); STEP8(r6); STEP8(r7);                               \
  } while(0)

  if (tid == 0){ flg[0] = 0; flg[1] = -1; }   // chunk 0 produced below; none consumed

  if (wid == 1){
    // -------- producer setup + chunk 0 (round 6 verbatim) --------
    fc16 = __half_as_ushort(__float2half(-1.4426950408889634f * fcb[0]));
    XLOAD(0);
    FILL(0);
    XLOAD(1);                 // prefetch chunk 1 (consumed next FILL)
  } else {
    // -------- consumer setup (k_rec7 verbatim) --------
    const int q  = lane & 3;
    const int j  = lane >> 2;             // 0..15 (13..15 padding)
    const int jc = (j < 13) ? j : 12;
    e = (lane == 52) ? 52 : q*13 + jc;
    const float kq = (q==2) ? -2.8853900817779268f : -1.4426950408889634f;
    gm = (q==2) ? -5.7707801635558536f : 1.f;
    ga = (q==2) ?  2.8853900817779268f : 0.f;
    fcbias = -1.4426950408889634f * fcb[0];
    const float* wsrc = (lane == 52) ? fcw : (Whh + (size_t)e*13);
    #pragma unroll
    for (int k=0;k<13;k++) w[k] = wsrc[k]*kq;
  }
  __syncthreads();                                  // flags + chunk 0 visible

  if (wid == 1){
    // -------- producer loop: chunks 1..31, flag-gated --------
    volatile int* cf = &flg[1];
    volatile int* pf = &flg[0];
    for (int pch=1; pch<32; ++pch){
      if (pch >= 2){
        while (*cf < pch-2) { }                     // buffer pch&1 free?
        asm volatile("" ::: "memory");
      }
      FILL(pch&1);                                  // chunk pch (uses prefetched xr)
      if (pch < 31) XLOAD(pch+1);                   // prefetch chunk pch+1
      asm volatile("s_waitcnt lgkmcnt(0)" ::: "memory");  // data writes retired
      __builtin_amdgcn_sched_barrier(0);
      *pf = pch;                                    // publish
    }
  } else {
    // -------- consumer loop: chunks 0..31, flag-gated, NO drains --------
    volatile int* pf = &flg[0];
    volatile int* cf = &flg[1];
    for (int cch=0; cch<32; ++cch){
      while (*pf < cch) { }                         // produced? (1 read when early)
      asm volatile("" ::: "memory");
      __builtin_amdgcn_sched_barrier(0);            // no ds_read hoist (rule #18)
      CONSUME(cch&1);                               // chunk cch (byte-identical)
      __builtin_amdgcn_sched_barrier(0);            // reads done before signal
      *cf = cch;                                    // release buffer
    }

    // epilogue: out[2047] = sigmoid(fc_b + fc_w·h_2047); lane 52 stores p0..p6 + r
    float s = fcbias;
    s = fmaf(w[0],  hb0,  s);
    s = fmaf(w[1],  hb1,  s);
    s = fmaf(w[2],  hb2,  s);
    s = fmaf(w[3],  hb3,  s);
    s = fmaf(w[4],  hb4,  s);
    s = fmaf(w[5],  hb5,  s);
    s = fmaf(w[6],  hb6,  s);
    s = fmaf(w[7],  hb7,  s);
    s = fmaf(w[8],  hb8,  s);
    s = fmaf(w[9],  hb9,  s);
    s = fmaf(w[10], hb10, s);
    s = fmaf(w[11], hb11, s);
    s = fmaf(w[12], hb12, s);
    float r = frcp(1.f + fexp2(s));
    if (lane == 52){
      float4* o4 = (float4*)op;                     // op == out + b*TT + 2040 here
      o4[0] = make_float4(p0,p1,p2,p3);
      o4[1] = make_float4(p4,p5,p6,r);
    }
  }

#undef CONSUME
#undef STEP8
#undef STEP
#undef CAPTURE
#undef FILL
#undef XLOAD
#undef XLO
#undef XHI
}

extern "C" void kernel_launch(void* const* d_in, const int* in_sizes, int n_in,
                              void* d_out, int out_size, void* d_ws, size_t ws_size,
                              hipStream_t stream)
{
  const float* x   = (const float*)d_in[0];
  const float* Wih = (const float*)d_in[1];
  const float* Whh = (const float*)d_in[2];
  const float* bih = (const float*)d_in[3];
  const float* bhh = (const float*)d_in[4];
  const float* fcw = (const float*)d_in[5];
  const float* fcb = (const float*)d_in[6];
  float* out = (float*)d_out;

  (void)d_ws; (void)ws_size;   // fully fused: no workspace
  k_pcf<<<dim3(BB), dim3(128), 0, stream>>>(x, Wih, Whh, bih, bhh, fcw, fcb, out);
}

// Round 14
// 307.800 us; speedup vs baseline: 1.0114x; 1.0114x over previous
//
#include <hip/hip_runtime.h>
#include <hip/hip_fp16.h>

#define BB 512
#define TT 2048

typedef _Float16 half2v __attribute__((ext_vector_type(2)));

// ---------- fast math helpers ----------
__device__ __forceinline__ float fexp2(float x){ return __builtin_amdgcn_exp2f(x); }
__device__ __forceinline__ float frcp(float x){ return __builtin_amdgcn_rcpf(x); }

#define QB(v, ctrl) __int_as_float(__builtin_amdgcn_mov_dpp(__float_as_int(v), (ctrl), 0xF, 0xF, true))
#define RL(v, l)    __builtin_amdgcn_readlane((v), (l))

// ---------- fused producer/consumer (round-6 optimum — FINAL) ----------
// Block = 128 threads (2 waves) per batch element b.
//   Consumer seed path is byte-identical to the proven 205us k_rec7 (f16 rows,
//   uint4/ds_read_b128 loads, 848B/tg layout); producer emits the exact k_xg3
//   row format into a double-buffered LDS chunk (2 x 8 tg x 424 ushort = 13.6KB).
//   producer (wave 1): 52 dots of 13 per chunk (weights via scalar cache, x via
//     13 coalesced per-lane dwords prefetched one chunk ahead) + f16 cvt +
//     ds_write_b16 -> always ~10K cy early vs the consumer's ~15.4K cy chunk.
//   consumer (wave 0): the serial recurrence. lane 4j+q = gate q of unit j;
//     lane 52 computes the fused FC output in the same instruction stream.
//   sync: 1 __syncthreads per 64 steps, double-buffered.
// FLOOR STATEMENT: latency-bound, not counter-bound (VALUBusy 39%, HBM 1.7%).
// 2048 serial steps x ~240cy chain (readlane -> depth-6 FMA dot -> exp2/rcp ->
// DPP -> c-update -> exp2/rcp -> h -> readlane) + ~35cy/step co-residency cost.
// Falsified alternatives: in-wave self-production (r1/r11: -100us), dual-chain
// (r5: -150us), f32 LDS seeds (r2-4: -50us), setprio (r7/8: -50us), I$ shrink
// (r7: -53us), early-XLOAD (r9: 0), CH=128 (r10: -100us), flag-sync (r13: 0).
__global__ __launch_bounds__(128, 1) void k_pc(
    const float* __restrict__ x,
    const float* __restrict__ Wih,
    const float* __restrict__ Whh,
    const float* __restrict__ bih,
    const float* __restrict__ bhh,
    const float* __restrict__ fcw,
    const float* __restrict__ fcb,
    float* __restrict__ out)
{
  __shared__ unsigned short xgb[2][8][424];   // [buf][tg][53 rows x 8 u]

  const int tid  = threadIdx.x;
  const int wid  = tid >> 6;
  const int lane = tid & 63;
  const int b    = blockIdx.x;

  // ---- producer state (persists across chunk loop)
  float xr[13];
  const int  tgl = lane >> 3, u = lane & 7;
  const float* xbase = x + ((size_t)b*TT + tgl*8 + u)*13;   // t = c*64 + tgl*8 + u
  unsigned short fc16 = 0;

  // ---- consumer state (persists across chunk loop; k_rec7 verbatim)
  float w[13];
  float gm = 1.f, ga = 0.f, fcbias = 0.f;
  int   e = 0;
  float h = 0.f, c_ = 0.f;            // c_ carries -2*log2e*c
  float hb0=0,hb1=0,hb2=0,hb3=0,hb4=0,hb5=0,hb6=0,hb7=0,hb8=0,hb9=0,hb10=0,hb11=0,hb12=0;
  float p0=0,p1=0,p2=0,p3=0,p4=0,p5=0,p6=0,p7=0;
  float* op = out + (size_t)b*TT;
  bool first = true;

// producer: load chunk c_'s 13 x values (coalesced per-lane dwords; issued one
// chunk ahead -- the full consumer chunk (~15K cy) covers HBM latency)
#define XLOAD(c_) do {                                                        \
    const float* p_ = xbase + (size_t)(c_)*64*13;                             \
    _Pragma("unroll")                                                         \
    for (int k=0;k<13;++k) xr[k] = p_[k];                                     \
  } while(0)

// producer: compute + write one chunk in the exact k_xg3 row format
#define FILL(bi_) do {                                                        \
    unsigned short* dst_ = &xgb[bi_][tgl][0];                                 \
    _Pragma("unroll 4")                                                       \
    for (int g=0; g<52; ++g){                                                 \
      float acc = bih[g] + bhh[g];                                            \
      _Pragma("unroll")                                                       \
      for (int k=0;k<13;++k) acc = fmaf(Wih[g*13+k], xr[k], acc);             \
      const float sc = (g>=26 && g<39) ? -2.8853900817779268f                 \
                                       : -1.4426950408889634f;                \
      dst_[g*8 + u] = __half_as_ushort(__float2half(acc*sc));                 \
    }                                                                         \
    dst_[52*8 + u] = fc16;                                                    \
  } while(0)

#define CAPTURE(gv_, u_) do {                                                 \
    if ((u_)==1) p0=(gv_); else if ((u_)==2) p1=(gv_);                        \
    else if ((u_)==3) p2=(gv_); else if ((u_)==4) p3=(gv_);                   \
    else if ((u_)==5) p4=(gv_); else if ((u_)==6) p5=(gv_);                   \
    else if ((u_)==7) p6=(gv_);                                               \
    else { p7=(gv_);                                                          \
      if (!first){                                                            \
        if (lane == 52){                                                      \
          float4* o4 = (float4*)op;                                           \
          o4[0] = make_float4(p0,p1,p2,p3);                                   \
          o4[1] = make_float4(p4,p5,p6,p7);                                   \
        }                                                                     \
        op += 8;                                                              \
      }                                                                       \
      first = false;                                                          \
    }                                                                         \
  } while(0)

#define STEP(xv_, u_) do {                                                    \
    float dA = fmaf(w[0], hb0, (xv_));                                        \
    dA = fmaf(w[1], hb1, dA);                                                 \
    dA = fmaf(w[2], hb2, dA);                                                 \
    dA = fmaf(w[3], hb3, dA);                                                 \
    dA = fmaf(w[4], hb4, dA);                                                 \
    float dB = w[5]*hb5;                                                      \
    dB = fmaf(w[6], hb6, dB);                                                 \
    dB = fmaf(w[7], hb7, dB);                                                 \
    dB = fmaf(w[8], hb8, dB);                                                 \
    float dC = w[9]*hb9;                                                      \
    dC = fmaf(w[10], hb10, dC);                                               \
    dC = fmaf(w[11], hb11, dC);                                               \
    dC = fmaf(w[12], hb12, dC);                                               \
    float s  = (dB + dC) + dA;                                                \
    float r  = frcp(1.f + fexp2(s));                                          \
    float g  = fmaf(gm, r, ga);                                               \
    CAPTURE(g, u_);                                                           \
    float ggb = QB(g, 0xAA);                                                  \
    float gfb = QB(g, 0x55);                                                  \
    float gob = QB(g, 0xFF);                                                  \
    float go2 = gob + gob;                                                    \
    c_ = fmaf(gfb, c_, g*ggb);                                                \
    float r2 = frcp(1.f + fexp2(c_));                                         \
    h = fmaf(go2, r2, -gob);                                                  \
    int hv_ = __float_as_int(h);                                              \
    hb0  = __int_as_float(RL(hv_, 0));                                        \
    hb1  = __int_as_float(RL(hv_, 4));                                        \
    hb2  = __int_as_float(RL(hv_, 8));                                        \
    hb3  = __int_as_float(RL(hv_, 12));                                       \
    hb4  = __int_as_float(RL(hv_, 16));                                       \
    hb5  = __int_as_float(RL(hv_, 20));                                       \
    hb6  = __int_as_float(RL(hv_, 24));                                       \
    hb7  = __int_as_float(RL(hv_, 28));                                       \
    hb8  = __int_as_float(RL(hv_, 32));                                       \
    hb9  = __int_as_float(RL(hv_, 36));                                       \
    hb10 = __int_as_float(RL(hv_, 40));                                       \
    hb11 = __int_as_float(RL(hv_, 44));                                       \
    hb12 = __int_as_float(RL(hv_, 48));                                       \
  } while(0)

#define XLO(w_) (float)(__builtin_bit_cast(half2v, (w_)).x)
#define XHI(w_) (float)(__builtin_bit_cast(half2v, (w_)).y)

#define STEP8(Q) do {                                                         \
    STEP(XLO(Q.x), 0); STEP(XHI(Q.x), 1);                                     \
    STEP(XLO(Q.y), 2); STEP(XHI(Q.y), 3);                                     \
    STEP(XLO(Q.z), 4); STEP(XHI(Q.z), 5);                                     \
    STEP(XLO(Q.w), 6); STEP(XHI(Q.w), 7);                                     \
  } while(0)

// consumer: one chunk = 8 tg rows, k_rec7's uint4 row loads from LDS
#define CONSUME(bi_) do {                                                     \
    const char* base_ = (const char*)&xgb[bi_][0][0] + (size_t)e*16;          \
    uint4 r0 = *(const uint4*)(base_ + 0*848);                                \
    uint4 r1 = *(const uint4*)(base_ + 1*848);                                \
    uint4 r2 = *(const uint4*)(base_ + 2*848);                                \
    uint4 r3 = *(const uint4*)(base_ + 3*848);                                \
    uint4 r4 = *(const uint4*)(base_ + 4*848);                                \
    uint4 r5 = *(const uint4*)(base_ + 5*848);                                \
    uint4 r6 = *(const uint4*)(base_ + 6*848);                                \
    uint4 r7 = *(const uint4*)(base_ + 7*848);                                \
    STEP8(r0); STEP8(r1); STEP8(r2); STEP8(r3);                               \
    STEP8(r4); STEP8(r5); STEP8(r6); STEP8(r7);                               \
  } while(0)

  if (wid == 1){
    // -------- producer setup + chunk 0 --------
    fc16 = __half_as_ushort(__float2half(-1.4426950408889634f * fcb[0]));
    XLOAD(0);
    FILL(0);
    XLOAD(1);                 // prefetch chunk 1 (consumed next FILL)
  } else {
    // -------- consumer setup (k_rec7 verbatim) --------
    const int q  = lane & 3;
    const int j  = lane >> 2;             // 0..15 (13..15 padding)
    const int jc = (j < 13) ? j : 12;
    e = (lane == 52) ? 52 : q*13 + jc;
    const float kq = (q==2) ? -2.8853900817779268f : -1.4426950408889634f;
    gm = (q==2) ? -5.7707801635558536f : 1.f;
    ga = (q==2) ?  2.8853900817779268f : 0.f;
    fcbias = -1.4426950408889634f * fcb[0];
    const float* wsrc = (lane == 52) ? fcw : (Whh + (size_t)e*13);
    #pragma unroll
    for (int k=0;k<13;k++) w[k] = wsrc[k]*kq;
  }
  __syncthreads();                                  // chunk 0 ready

  for (int c=0; c<31; ++c){
    if (wid == 1){
      FILL((c+1)&1);                                // chunk c+1 (uses prefetched xr)
      if (c < 30) XLOAD(c+2);                       // prefetch chunk c+2
    } else {
      CONSUME(c&1);                                 // chunk c
    }
    __syncthreads();                                // chunk c+1 ready
  }

  if (wid == 0){
    CONSUME(31&1);                                  // chunk 31

    // epilogue: out[2047] = sigmoid(fc_b + fc_w·h_2047); lane 52 stores p0..p6 + r
    float s = fcbias;
    s = fmaf(w[0],  hb0,  s);
    s = fmaf(w[1],  hb1,  s);
    s = fmaf(w[2],  hb2,  s);
    s = fmaf(w[3],  hb3,  s);
    s = fmaf(w[4],  hb4,  s);
    s = fmaf(w[5],  hb5,  s);
    s = fmaf(w[6],  hb6,  s);
    s = fmaf(w[7],  hb7,  s);
    s = fmaf(w[8],  hb8,  s);
    s = fmaf(w[9],  hb9,  s);
    s = fmaf(w[10], hb10, s);
    s = fmaf(w[11], hb11, s);
    s = fmaf(w[12], hb12, s);
    float r = frcp(1.f + fexp2(s));
    if (lane == 52){
      float4* o4 = (float4*)op;                     // op == out + b*TT + 2040 here
      o4[0] = make_float4(p0,p1,p2,p3);
      o4[1] = make_float4(p4,p5,p6,r);
    }
  }

#undef CONSUME
#undef STEP8
#undef STEP
#undef CAPTURE
#undef FILL
#undef XLOAD
#undef XLO
#undef XHI
}

extern "C" void kernel_launch(void* const* d_in, const int* in_sizes, int n_in,
                              void* d_out, int out_size, void* d_ws, size_t ws_size,
                              hipStream_t stream)
{
  const float* x   = (const float*)d_in[0];
  const float* Wih = (const float*)d_in[1];
  const float* Whh = (const float*)d_in[2];
  const float* bih = (const float*)d_in[3];
  const float* bhh = (const float*)d_in[4];
  const float* fcw = (const float*)d_in[5];
  const float* fcb = (const float*)d_in[6];
  float* out = (float*)d_out;

  (void)d_ws; (void)ws_size;   // fully fused: no workspace
  k_pc<<<dim3(BB), dim3(128), 0, stream>>>(x, Wih, Whh, bih, bhh, fcw, fcb, out);
}